// Round 8
// baseline (208.483 us; speedup 1.0000x reference)
//
#include <hip/hip_runtime.h>

typedef unsigned short u16;
typedef unsigned int u32;
// may_alias: reinterpret-cast LDS/global vector access (prevent TBAA reorder).
typedef __attribute__((ext_vector_type(8), may_alias)) short short8;
typedef __attribute__((ext_vector_type(4), may_alias)) u32 uint4_ma;
typedef __attribute__((ext_vector_type(2), may_alias)) u32 uint2_ma;
typedef __attribute__((ext_vector_type(4), may_alias)) float floatx4_ma;
typedef __attribute__((ext_vector_type(4))) float floatx4;

#define DEV static __device__ __forceinline__

constexpr int S = 128, NRES = 256, D = 256, H = 8;
constexpr int M = S * NRES;                        // 32768 rows
constexpr float ATT_SCALE = 0.17677669529663687f;  // 1/sqrt(32)

DEV float bf2f(u16 h) {
  union { u32 u; float f; } v; v.u = ((u32)h) << 16; return v.f;
}
DEV u16 f2bf(float f) {
  union { float f; u32 u; } v; v.f = f;
  u32 u = v.u;
  return (u16)((u + 0x7fffu + ((u >> 16) & 1u)) >> 16);  // RNE
}

// ------------------------------------------------- weight pre-convert (once)
// f32 -> bf16 for wq|wk|wv|wo into ws. grid (64, 4), 256 thr, float4/thread.
__global__ __launch_bounds__(256) void wcvt_kernel(
    const float* __restrict__ w0, const float* __restrict__ w1,
    const float* __restrict__ w2, const float* __restrict__ w3,
    u16* __restrict__ dst) {
  const float* src = (blockIdx.y == 0) ? w0 : (blockIdx.y == 1) ? w1
                   : (blockIdx.y == 2) ? w2 : w3;
  const int idx = blockIdx.x * 256 + threadIdx.x;  // 0..16383, 4 elems each
  floatx4_ma f = ((const floatx4_ma*)src)[idx];
  uint2_ma o;
  o.x = (u32)f2bf(f[0]) | ((u32)f2bf(f[1]) << 16);
  o.y = (u32)f2bf(f[2]) | ((u32)f2bf(f[3]) << 16);
  ((uint2_ma*)(dst + (size_t)blockIdx.y * D * D))[idx] = o;
}

// ---------------------------------------------------------------- LayerNorm
// f32 in (d_in), bf16 out (ws). One wave per row of 256; float4/lane.
__global__ __launch_bounds__(256) void ln_kernel(const float* __restrict__ x,
                                                 const float* __restrict__ w,
                                                 const float* __restrict__ b,
                                                 u16* __restrict__ xn) {
  const int lane = threadIdx.x & 63;
  const int row = blockIdx.x * 4 + (threadIdx.x >> 6);
  floatx4_ma d = ((const floatx4_ma*)(x + (size_t)row * D))[lane];
  float s = d[0] + d[1] + d[2] + d[3];
  float ss = d[0] * d[0] + d[1] * d[1] + d[2] * d[2] + d[3] * d[3];
#pragma unroll
  for (int off = 32; off > 0; off >>= 1) {
    s += __shfl_xor(s, off, 64);
    ss += __shfl_xor(ss, off, 64);
  }
  const float mean = s * (1.0f / D);
  const float var = ss * (1.0f / D) - mean * mean;
  const float rstd = rsqrtf(var + 1e-5f);
  floatx4_ma wd = ((const floatx4_ma*)w)[lane];
  floatx4_ma bd = ((const floatx4_ma*)b)[lane];
  uint2_ma o;
  o.x = (u32)f2bf((d[0] - mean) * rstd * wd[0] + bd[0]) |
        ((u32)f2bf((d[1] - mean) * rstd * wd[1] + bd[1]) << 16);
  o.y = (u32)f2bf((d[2] - mean) * rstd * wd[2] + bd[2]) |
        ((u32)f2bf((d[3] - mean) * rstd * wd[3] + bd[3]) << 16);
  ((uint2_ma*)(xn + (size_t)row * D))[lane] = o;
}

// ------------------------------------------------------- B staging (128 rows)
// bf16 W' rows -> LDS via async DMA, XOR-granule swizzle
// LDS[r][g] = global[r][g ^ (r&7)] (16B granules, 512B rows).
DEV void stage_B_async(const u16* Brows, u16* Bs, int lane, int wv) {
  const char* Bg = (const char*)Brows;
  const int gl = lane & 31;
  const int rofs = lane >> 5;
#pragma unroll
  for (int it = 0; it < 16; ++it) {
    const int idx = wv * 16 + it;      // 1KB chunk 0..63
    const int r = idx * 2 + rofs;      // row 0..127
    const int gofs = r * 512 + ((gl ^ (r & 7)) << 4);
    const int lofs = idx * 1024;       // wave-uniform base (+lane*16 by HW)
    __builtin_amdgcn_global_load_lds(
        (const __attribute__((address_space(1))) u32*)(Bg + gofs),
        (__attribute__((address_space(3))) u32*)((char*)Bs + lofs), 16, 0, 0);
  }
}

// 128x128 MFMA core. A-frags DIRECT FROM GLOBAL (16B contiguous per lane),
// manual 2-stage prefetch; B-frags from swizzled LDS. acc[i][j] 4x4 tiles.
DEV void mfma_core128(const u16* A /*block m0 rows*/, const u16* Bs,
                      int lane, int wv, floatx4 acc[4][4]) {
  const int wr = wv >> 1, wc = wv & 1;
  const int q4 = lane >> 4, r16 = lane & 15;
  const u16* Arow = A + (size_t)(wr * 64 + r16) * 256 + q4 * 8;
  short8 a_cur[4], a_nxt[4];
#pragma unroll
  for (int i = 0; i < 4; ++i)
    a_cur[i] = *(const short8*)(Arow + i * 16 * 256);
#pragma unroll 1
  for (int kk = 0; kk < 8; ++kk) {
    if (kk < 7) {
#pragma unroll
      for (int i = 0; i < 4; ++i)
        a_nxt[i] = *(const short8*)(Arow + i * 16 * 256 + (kk + 1) * 32);
    }
    const int G = kk * 4 + q4;
    short8 b[4];
#pragma unroll
    for (int j = 0; j < 4; ++j) {
      const int nr = wc * 64 + j * 16 + r16;
      b[j] = *(const short8*)(Bs + nr * 256 + ((G ^ (nr & 7)) << 3));
    }
#pragma unroll
    for (int i = 0; i < 4; ++i)
#pragma unroll
      for (int j = 0; j < 4; ++j)
        acc[i][j] = __builtin_amdgcn_mfma_f32_16x16x32_bf16(a_cur[i], b[j], acc[i][j], 0, 0, 0);
#pragma unroll
    for (int i = 0; i < 4; ++i) a_cur[i] = a_nxt[i];
  }
}

// ------------------------------------------------------------ QKV GEMM v2
// C[m][n] = sum_k A[m][k]*W[n][k]. 128x128 block; W' bf16 (ws). grid (M/128,2,3)
__global__ __launch_bounds__(256) void gemm_qkv_kernel(
    const u16* __restrict__ A, const u16* __restrict__ Wbf,
    u16* __restrict__ C0, u16* __restrict__ C1, u16* __restrict__ C2) {
  alignas(16) __shared__ u16 Bs[128 * 256];
  const int tid = threadIdx.x;
  const int lane = tid & 63;
  const int wv = tid >> 6;
  const int m0 = blockIdx.x * 128;
  const int n0 = blockIdx.y * 128;
  const u16* Wp = Wbf + (size_t)blockIdx.z * D * D;
  u16* Cp = (blockIdx.z == 0) ? C0 : ((blockIdx.z == 1) ? C1 : C2);

  stage_B_async(Wp + (size_t)n0 * 256, Bs, lane, wv);
  __syncthreads();

  floatx4 acc[4][4] = {};
  mfma_core128(A + (size_t)m0 * 256, Bs, lane, wv, acc);

  const int wr = wv >> 1, wc = wv & 1;
  const int q4 = lane >> 4, r16 = lane & 15;
#pragma unroll
  for (int j = 0; j < 4; ++j) {
    const int col = n0 + wc * 64 + j * 16 + r16;
#pragma unroll
    for (int i = 0; i < 4; ++i) {
      const int mbase = m0 + wr * 64 + i * 16 + q4 * 4;
#pragma unroll
      for (int r = 0; r < 4; ++r)
        Cp[(size_t)(mbase + r) * 256 + col] = f2bf(acc[i][j][r]);
    }
  }
}

// ------------------------------------------------------------ out-proj v2
// OUT(f32) = AO*WO^T + bo. Same 128x128 structure. grid (M/128, 2)
__global__ __launch_bounds__(256) void gemm_out_kernel(
    const u16* __restrict__ AO, const u16* __restrict__ Wobf,
    const float* __restrict__ bo, float* __restrict__ OUT) {
  alignas(16) __shared__ u16 Bs[128 * 256];
  const int tid = threadIdx.x;
  const int lane = tid & 63;
  const int wv = tid >> 6;
  const int m0 = blockIdx.x * 128;
  const int n0 = blockIdx.y * 128;

  stage_B_async(Wobf + (size_t)n0 * 256, Bs, lane, wv);
  __syncthreads();

  floatx4 acc[4][4] = {};
  mfma_core128(AO + (size_t)m0 * 256, Bs, lane, wv, acc);

  const int wr = wv >> 1, wc = wv & 1;
  const int q4 = lane >> 4, r16 = lane & 15;
#pragma unroll
  for (int j = 0; j < 4; ++j) {
    const int col = n0 + wc * 64 + j * 16 + r16;
    const float bv = bo[col];
#pragma unroll
    for (int i = 0; i < 4; ++i) {
      const int mbase = m0 + wr * 64 + i * 16 + q4 * 4;
#pragma unroll
      for (int r = 0; r < 4; ++r)
        OUT[(size_t)(mbase + r) * 256 + col] = acc[i][j][r] + bv;
    }
  }
}

// ------------------------------------------------------------ row attention
// one block per (h, s). K + V^T staged to LDS, register softmax, P via
// per-wave swizzled LDS with PER-WAVE s_waitcnt fences (Psh is wave-private;
// no block barrier needed in the loop). Q-frags prefetched for all 4 iters.
__global__ __launch_bounds__(256) void attn_kernel(
    const u16* __restrict__ Q, const u16* __restrict__ K, const u16* __restrict__ V,
    u16* __restrict__ O) {
  alignas(16) __shared__ u16 Ksh[256 * 32];      // [kj][d]
  alignas(16) __shared__ u16 Vt[32 * 264];       // [d][kj], +8 pad
  alignas(16) __shared__ u16 Psh[4][16 * 256];   // per-wave P, swizzled
  const int h = blockIdx.x;
  const int s = blockIdx.y;
  const int tid = threadIdx.x;
  const int lane = tid & 63;
  const int wv = tid >> 6;
  const int q4 = lane >> 4, r16 = lane & 15;
  const size_t rowbase = (size_t)s * 256;

  {  // stage K and V (transposed)
    const int r4 = tid >> 2;
    const int ch = tid & 3;
#pragma unroll
    for (int p = 0; p < 4; ++p) {
      const int row = p * 64 + r4;
      const size_t gofs = (rowbase + row) * 256 + h * 32 + ch * 8;
      *(uint4_ma*)(Ksh + row * 32 + ch * 8) = *(const uint4_ma*)(K + gofs);
      uint4_ma vvl = *(const uint4_ma*)(V + gofs);
      const u16* ve = (const u16*)&vvl;
#pragma unroll
      for (int e = 0; e < 8; ++e)
        Vt[(ch * 8 + e) * 264 + row] = ve[e];
    }
  }
  // Prefetch Q fragments for all 4 iterations (removes per-iter load latency)
  short8 aqs[4];
#pragma unroll
  for (int mt = 0; mt < 4; ++mt)
    aqs[mt] = *(const short8*)(Q + (rowbase + (mt * 4 + wv) * 16 + r16) * 256 + h * 32 + q4 * 8);
  __syncthreads();

  u16* P = Psh[wv];
#pragma unroll 1
  for (int mt0 = 0; mt0 < 4; ++mt0) {
    const int qbase = (mt0 * 4 + wv) * 16;
    floatx4 sc[16];
#pragma unroll
    for (int t = 0; t < 16; ++t) {
      const short8 bk = *(const short8*)(Ksh + (t * 16 + r16) * 32 + q4 * 8);
      floatx4 z = {0.f, 0.f, 0.f, 0.f};
      sc[t] = __builtin_amdgcn_mfma_f32_16x16x32_bf16(aqs[mt0], bk, z, 0, 0, 0);
    }
    float inv[4];
#pragma unroll
    for (int r = 0; r < 4; ++r) {
      float mx = sc[0][r];
#pragma unroll
      for (int t = 1; t < 16; ++t) mx = fmaxf(mx, sc[t][r]);
      mx = fmaxf(mx, __shfl_xor(mx, 1, 64));
      mx = fmaxf(mx, __shfl_xor(mx, 2, 64));
      mx = fmaxf(mx, __shfl_xor(mx, 4, 64));
      mx = fmaxf(mx, __shfl_xor(mx, 8, 64));
      float sum = 0.f;
#pragma unroll
      for (int t = 0; t < 16; ++t) {
        const float p = __expf((sc[t][r] - mx) * ATT_SCALE);
        sc[t][r] = p;
        sum += p;
      }
      sum += __shfl_xor(sum, 1, 64);
      sum += __shfl_xor(sum, 2, 64);
      sum += __shfl_xor(sum, 4, 64);
      sum += __shfl_xor(sum, 8, 64);
      inv[r] = 1.0f / sum;
    }
#pragma unroll
    for (int t = 0; t < 16; ++t) {
      const int col = t * 16 + r16;
      const int g = col >> 3, cb = col & 7;
#pragma unroll
      for (int r = 0; r < 4; ++r) {
        const int m_ = q4 * 4 + r;
        P[m_ * 256 + ((g ^ (m_ & 7)) << 3) + cb] = f2bf(sc[t][r]);
      }
    }
    // Per-wave fence: Psh is wave-private; drain DS writes + compiler barrier.
    asm volatile("s_waitcnt lgkmcnt(0)" ::: "memory");
    floatx4 o0 = {0.f, 0.f, 0.f, 0.f}, o1 = {0.f, 0.f, 0.f, 0.f};
#pragma unroll
    for (int kk = 0; kk < 8; ++kk) {
      const int G = kk * 4 + q4;
      const short8 ap = *(const short8*)(P + r16 * 256 + ((G ^ (r16 & 7)) << 3));
      const short8 bv0 = *(const short8*)(Vt + r16 * 264 + kk * 32 + q4 * 8);
      const short8 bv1 = *(const short8*)(Vt + (16 + r16) * 264 + kk * 32 + q4 * 8);
      o0 = __builtin_amdgcn_mfma_f32_16x16x32_bf16(ap, bv0, o0, 0, 0, 0);
      o1 = __builtin_amdgcn_mfma_f32_16x16x32_bf16(ap, bv1, o1, 0, 0, 0);
    }
#pragma unroll
    for (int r = 0; r < 4; ++r) {
      const size_t ob = (rowbase + qbase + q4 * 4 + r) * 256 + h * 32;
      O[ob + r16] = f2bf(o0[r] * inv[r]);
      O[ob + 16 + r16] = f2bf(o1[r] * inv[r]);
    }
    // Drain this iter's P reads before next iter's writes (per-wave).
    asm volatile("s_waitcnt lgkmcnt(0)" ::: "memory");
  }
}

// ---------------------------------------------------------------- launch
extern "C" void kernel_launch(void* const* d_in, const int* in_sizes, int n_in,
                              void* d_out, int out_size, void* d_ws, size_t ws_size,
                              hipStream_t stream) {
  (void)in_sizes; (void)n_in; (void)out_size;
  const float* msa = (const float*)d_in[0];
  const float* lnw = (const float*)d_in[1];
  const float* lnb = (const float*)d_in[2];
  const float* wq = (const float*)d_in[3];
  const float* wk = (const float*)d_in[4];
  const float* wvp = (const float*)d_in[5];
  const float* wo = (const float*)d_in[6];
  const float* bo = (const float*)d_in[7];
  float* out = (float*)d_out;

  // ws layout: W' bf16 (4*65536) | xn | q | k | v  (per-chunk, bf16)
  u16* Wbf = (u16*)d_ws;
  const size_t wElems = (size_t)4 * D * D;  // 262144
  int CS = S;  // s-rows per chunk, pow2
  while (CS > 1 && wElems * 2 + (size_t)CS * 524288ull > ws_size) CS >>= 1;
  const int nch = S / CS;
  const size_t chunkElems = (size_t)CS * NRES * D;
  u16* xnc = Wbf + wElems;
  u16* qc = xnc + chunkElems;
  u16* kc = qc + chunkElems;
  u16* vc = kc + chunkElems;
  u16* aoc = xnc;  // xn dead after QKV GEMM

  wcvt_kernel<<<dim3(64, 4), 256, 0, stream>>>(wq, wk, wvp, wo, Wbf);

  const int mrows = CS * NRES;
  for (int c = 0; c < nch; ++c) {
    const size_t row0 = (size_t)c * mrows;
    ln_kernel<<<mrows / 4, 256, 0, stream>>>(msa + row0 * D, lnw, lnb, xnc);
    gemm_qkv_kernel<<<dim3(mrows / 128, 2, 3), 256, 0, stream>>>(xnc, Wbf, qc, kc, vc);
    attn_kernel<<<dim3(H, CS), 256, 0, stream>>>(qc, kc, vc, aoc);
    gemm_out_kernel<<<dim3(mrows / 128, 2), 256, 0, stream>>>(
        aoc, Wbf + (size_t)3 * D * D, bo, out + row0 * D);
  }
}